// Round 1
// baseline (189.384 us; speedup 1.0000x reference)
//
#include <hip/hip_runtime.h>
#include <hip/hip_bf16.h>

typedef __bf16 bf16;
typedef __bf16 bf16x8 __attribute__((ext_vector_type(8)));
typedef float f32x4 __attribute__((ext_vector_type(4)));
typedef unsigned short u16x8 __attribute__((ext_vector_type(8)));

#define EXP2(x) __builtin_amdgcn_exp2f(x)

static __device__ __forceinline__ f32x4 mfma16(bf16x8 a, bf16x8 b, f32x4 c) {
    return __builtin_amdgcn_mfma_f32_16x16x32_bf16(a, b, c, 0, 0, 0);
}

// ---------------- Kernel 1: weight convert (+ fold softmax scale*log2e into Q rows) ----
__global__ __launch_bounds__(256) void prep_w_kernel(const float* __restrict__ qkv_w,
                                                     const float* __restrict__ proj_w,
                                                     bf16* __restrict__ wqkv,
                                                     bf16* __restrict__ wproj) {
    int idx = blockIdx.x * 256 + threadIdx.x;
    const float QSCALE = 0.17677669529663689f * 1.4426950408889634f; // hd^-0.5 * log2(e)
    if (idx < 768 * 256) {
        float v = qkv_w[idx];
        if (idx < 256 * 256) v *= QSCALE;   // rows o<256 are the Q projection
        wqkv[idx] = (bf16)v;
    } else {
        int j = idx - 768 * 256;
        wproj[j] = (bf16)proj_w[j];
    }
}

// ---------------- Kernel 2: x [2][256][4096] f32 -> xT [2][4096][256] bf16 ------------
__global__ __launch_bounds__(256) void transpose_x_kernel(const float* __restrict__ x,
                                                          bf16* __restrict__ xT) {
    __shared__ float tile[32][33];
    int b = blockIdx.z, cb = blockIdx.y * 32, nb = blockIdx.x * 32;
    int t = threadIdx.x;
    int tn = t & 31, tc = t >> 5;   // tc in [0,8)
    const float* src = x + ((size_t)b * 256 + cb) * 4096 + nb;
#pragma unroll
    for (int i = 0; i < 4; i++)
        tile[tc + i * 8][tn] = src[(size_t)(tc + i * 8) * 4096 + tn];
    __syncthreads();
    bf16* dst = xT + ((size_t)b * 4096 + nb) * 256 + cb;
#pragma unroll
    for (int i = 0; i < 4; i++)
        dst[(size_t)(tc + i * 8) * 256 + tn] = (bf16)tile[tn][tc + i * 8];
}

// ---------------- Kernel 3: QKV GEMM.  D[n][o] = xT[n][c] * wqkv[o][c]^T --------------
// block tile 128n x 128o, 4 waves (2x2), wave tile 64x64 (rt,cg in [0,4))
__global__ __launch_bounds__(256) void qkv_gemm_kernel(const bf16* __restrict__ xT,
                                                       const bf16* __restrict__ w,
                                                       bf16* __restrict__ Q,
                                                       bf16* __restrict__ K,
                                                       bf16* __restrict__ V) {
    int b = blockIdx.z;
    int nb = blockIdx.x * 128, ob = blockIdx.y * 128;
    int t = threadIdx.x, wid = t >> 6, lane = t & 63;
    int l15 = lane & 15, g = lane >> 4;
    int wr = wid >> 1, wc = wid & 1;
    const bf16* xrow = xT + ((size_t)b * 4096 + nb + wr * 64 + l15) * 256 + g * 8;
    const bf16* wrow = w + (size_t)(ob + wc * 64 + l15) * 256 + g * 8;
    f32x4 acc[4][4] = {};
    for (int k0 = 0; k0 < 256; k0 += 32) {
        bf16x8 a[4], bb[4];
#pragma unroll
        for (int rt = 0; rt < 4; rt++) a[rt] = *(const bf16x8*)(xrow + rt * 16 * 256 + k0);
#pragma unroll
        for (int cg = 0; cg < 4; cg++) bb[cg] = *(const bf16x8*)(wrow + cg * 16 * 256 + k0);
#pragma unroll
        for (int rt = 0; rt < 4; rt++)
#pragma unroll
            for (int cg = 0; cg < 4; cg++)
                acc[rt][cg] = mfma16(a[rt], bb[cg], acc[rt][cg]);
    }
    // D row = n = (g*4+i) + rt*16 (+wr*64+nb); col = o = l15 + cg*16 (+wc*64+ob)
#pragma unroll
    for (int rt = 0; rt < 4; rt++) {
#pragma unroll
        for (int cg = 0; cg < 4; cg++) {
            int o = ob + wc * 64 + cg * 16 + l15;
            int tsel = o >> 8;           // 0=Q 1=K 2=V
            int h = (o >> 5) & 7;
            int d = o & 31;
            bf16* dst = (tsel == 0 ? Q : (tsel == 1 ? K : V));
#pragma unroll
            for (int i = 0; i < 4; i++) {
                int n = nb + wr * 64 + rt * 16 + g * 4 + i;
                dst[(((size_t)b * 8 + h) * 4096 + n) * 32 + d] = (bf16)acc[rt][cg][i];
            }
        }
    }
}

// ---------------- Kernel 4: V [bh][4096][32] -> VT [bh][32][4096] ---------------------
__global__ __launch_bounds__(256) void transpose_v_kernel(const bf16* __restrict__ V,
                                                          bf16* __restrict__ VT) {
    __shared__ unsigned short tile[64][40];
    int bh = blockIdx.y, nb = blockIdx.x * 64;
    int t = threadIdx.x;
    int rn = t >> 2, d0 = (t & 3) * 8;
    u16x8 vv = *(const u16x8*)((const unsigned short*)V + ((size_t)bh * 4096 + nb + rn) * 32 + d0);
#pragma unroll
    for (int j = 0; j < 8; j++) tile[rn][d0 + j] = vv[j];
    __syncthreads();
    int d = t >> 3, n0 = (t & 7) * 8;
    u16x8 o;
#pragma unroll
    for (int j = 0; j < 8; j++) o[j] = tile[n0 + j][d];
    *(u16x8*)((unsigned short*)VT + ((size_t)bh * 32 + d) * 4096 + nb + n0) = o;
}

// ---------------- Kernel 5: flash attention -------------------------------------------
// grid (32 qblocks, 16 bh), 256 thr = 4 waves, QBLK=128 (32 q-rows/wave), KBLK=64
__global__ __launch_bounds__(256) void attn_kernel(const bf16* __restrict__ Q,
                                                   const bf16* __restrict__ K,
                                                   const bf16* __restrict__ VT,
                                                   bf16* __restrict__ attT) {
    __shared__ __align__(16) bf16 Klds[64 * 40];       // [n][d] pad 40
    __shared__ __align__(16) bf16 Vlds[32 * 72];       // [d][n] pad 72
    __shared__ __align__(16) bf16 plds[4][32 * 64];    // per-wave P, XOR-swizzled

    const int bh = blockIdx.y;
    const int qb = blockIdx.x * 128;
    const int t = threadIdx.x;
    const int wid = t >> 6;
    const int lane = t & 63;
    const int l15 = lane & 15;
    const int g = lane >> 4;

    const bf16* __restrict__ Qb = Q + (size_t)bh * 4096 * 32;
    const bf16* __restrict__ Kb = K + (size_t)bh * 4096 * 32;
    const bf16* __restrict__ Vb = VT + (size_t)bh * 4096 * 32;   // [32][4096]

    const int q0 = qb + wid * 32;
    bf16x8 qa[2];
    qa[0] = *(const bf16x8*)(Qb + (size_t)(q0 + l15) * 32 + g * 8);
    qa[1] = *(const bf16x8*)(Qb + (size_t)(q0 + 16 + l15) * 32 + g * 8);

    bf16x8 ones;
#pragma unroll
    for (int j = 0; j < 8; j++) ones[j] = (bf16)1.0f;

    f32x4 o_acc[2][2] = {};
    float m_run[2][4], l_run[2][4];
#pragma unroll
    for (int rt = 0; rt < 2; rt++)
#pragma unroll
        for (int i = 0; i < 4; i++) { m_run[rt][i] = -INFINITY; l_run[rt][i] = 0.f; }

    const int sn = t >> 2, sd0 = (t & 3) * 8;   // K staging: row, d-offset
    const int vd = t >> 3, vn0 = (t & 7) * 8;   // V staging: d-row, n-offset
    bf16* pw = &plds[wid][0];

    for (int kb = 0; kb < 4096; kb += 64) {
        __syncthreads();
        *(bf16x8*)(Klds + sn * 40 + sd0) = *(const bf16x8*)(Kb + (size_t)(kb + sn) * 32 + sd0);
        *(bf16x8*)(Vlds + vd * 72 + vn0) = *(const bf16x8*)(Vb + (size_t)vd * 4096 + kb + vn0);
        __syncthreads();

        // S = Q K^T   (Q pre-scaled by hd^-0.5*log2e)
        f32x4 s[2][4];
#pragma unroll
        for (int cg = 0; cg < 4; cg++) {
            bf16x8 kf = *(const bf16x8*)(Klds + (cg * 16 + l15) * 40 + g * 8);
            s[0][cg] = mfma16(qa[0], kf, f32x4{0.f, 0.f, 0.f, 0.f});
            s[1][cg] = mfma16(qa[1], kf, f32x4{0.f, 0.f, 0.f, 0.f});
        }
        // online softmax; rows r = rt*16 + g*4 + i, cols cg*16 + l15
#pragma unroll
        for (int rt = 0; rt < 2; rt++) {
            float tmax[4];
#pragma unroll
            for (int i = 0; i < 4; i++)
                tmax[i] = fmaxf(fmaxf(s[rt][0][i], s[rt][1][i]), fmaxf(s[rt][2][i], s[rt][3][i]));
#pragma unroll
            for (int off = 8; off >= 1; off >>= 1)
#pragma unroll
                for (int i = 0; i < 4; i++)
                    tmax[i] = fmaxf(tmax[i], __shfl_xor(tmax[i], off));
#pragma unroll
            for (int i = 0; i < 4; i++) {
                float mnew = fmaxf(m_run[rt][i], tmax[i]);
                float corr = EXP2(m_run[rt][i] - mnew);
                m_run[rt][i] = mnew;
                l_run[rt][i] *= corr;
                o_acc[rt][0][i] *= corr;
                o_acc[rt][1][i] *= corr;
#pragma unroll
                for (int cg = 0; cg < 4; cg++)
                    s[rt][cg][i] = EXP2(s[rt][cg][i] - mnew);
            }
            // write P (bf16) to swizzled per-wave LDS
#pragma unroll
            for (int cg = 0; cg < 4; cg++)
#pragma unroll
                for (int i = 0; i < 4; i++) {
                    int qr = rt * 16 + g * 4 + i;
                    int col = cg * 16 + l15;
                    pw[qr * 64 + (col ^ ((qr & 7) << 3))] = (bf16)s[rt][cg][i];
                }
        }
        asm volatile("s_waitcnt lgkmcnt(0)" ::: "memory");
        __builtin_amdgcn_sched_barrier(0);
        // O += P V ; row-sum via P*ones on the MFMA pipe
#pragma unroll
        for (int rt = 0; rt < 2; rt++) {
            f32x4 rs = {0.f, 0.f, 0.f, 0.f};
#pragma unroll
            for (int kk = 0; kk < 2; kk++) {
                int row = rt * 16 + l15;
                int colbase = kk * 32 + g * 8;
                bf16x8 pa = *(const bf16x8*)(pw + row * 64 + (colbase ^ ((l15 & 7) << 3)));
#pragma unroll
                for (int dcg = 0; dcg < 2; dcg++) {
                    bf16x8 vf = *(const bf16x8*)(Vlds + (dcg * 16 + l15) * 72 + kk * 32 + g * 8);
                    o_acc[rt][dcg] = mfma16(pa, vf, o_acc[rt][dcg]);
                }
                rs = mfma16(pa, ones, rs);
            }
#pragma unroll
            for (int i = 0; i < 4; i++) l_run[rt][i] += rs[i];
        }
    }
    // epilogue -> attT[b][n][c], c = h*32 + d
    const int b = bh >> 3, h = bh & 7;
#pragma unroll
    for (int rt = 0; rt < 2; rt++)
#pragma unroll
        for (int i = 0; i < 4; i++) {
            float inv = __builtin_amdgcn_rcpf(l_run[rt][i]);
            int n = q0 + rt * 16 + g * 4 + i;
#pragma unroll
            for (int dcg = 0; dcg < 2; dcg++) {
                int c = h * 32 + dcg * 16 + l15;
                attT[((size_t)b * 4096 + n) * 256 + c] = (bf16)(o_acc[rt][dcg][i] * inv);
            }
        }
}

// ---------------- Kernel 6: proj GEMM. out[b][o][n] = wproj[o][c] * att[c][n] + bias --
// block tile 64o x 128n, 4 waves (2x2), wave 32o x 64n (rt in [0,2), cg in [0,4))
__global__ __launch_bounds__(256) void proj_gemm_kernel(const bf16* __restrict__ attT,
                                                        const bf16* __restrict__ w,
                                                        const float* __restrict__ bias,
                                                        float* __restrict__ out) {
    int b = blockIdx.z;
    int nb = blockIdx.x * 128, ob = blockIdx.y * 64;
    int t = threadIdx.x, wid = t >> 6, lane = t & 63;
    int l15 = lane & 15, g = lane >> 4;
    int wr = wid >> 1, wc = wid & 1;
    const bf16* arow = w + (size_t)(ob + wr * 32 + l15) * 256 + g * 8;
    const bf16* brow = attT + ((size_t)b * 4096 + nb + wc * 64 + l15) * 256 + g * 8;
    f32x4 acc[2][4] = {};
    for (int k0 = 0; k0 < 256; k0 += 32) {
        bf16x8 a[2], bb[4];
#pragma unroll
        for (int rt = 0; rt < 2; rt++) a[rt] = *(const bf16x8*)(arow + rt * 16 * 256 + k0);
#pragma unroll
        for (int cg = 0; cg < 4; cg++) bb[cg] = *(const bf16x8*)(brow + cg * 16 * 256 + k0);
#pragma unroll
        for (int rt = 0; rt < 2; rt++)
#pragma unroll
            for (int cg = 0; cg < 4; cg++)
                acc[rt][cg] = mfma16(a[rt], bb[cg], acc[rt][cg]);
    }
#pragma unroll
    for (int rt = 0; rt < 2; rt++)
#pragma unroll
        for (int cg = 0; cg < 4; cg++)
#pragma unroll
            for (int i = 0; i < 4; i++) {
                int o = ob + wr * 32 + rt * 16 + g * 4 + i;
                int n = nb + wc * 64 + cg * 16 + l15;
                out[((size_t)b * 256 + o) * 4096 + n] = acc[rt][cg][i] + bias[o];
            }
}

// ---------------- launch --------------------------------------------------------------
extern "C" void kernel_launch(void* const* d_in, const int* in_sizes, int n_in,
                              void* d_out, int out_size, void* d_ws, size_t ws_size,
                              hipStream_t stream) {
    const float* x      = (const float*)d_in[0];
    const float* qkv_w  = (const float*)d_in[1];
    const float* proj_w = (const float*)d_in[2];
    const float* proj_b = (const float*)d_in[3];
    float* out = (float*)d_out;

    char* ws = (char*)d_ws;
    bf16* xT    = (bf16*)(ws);                    // 2*4096*256*2   = 4,194,304 B
    bf16* wqkv  = (bf16*)(ws + 4194304);          // 768*256*2      =   393,216 B
    bf16* wproj = (bf16*)(ws + 4587520);          // 256*256*2      =   131,072 B
    bf16* Qb    = (bf16*)(ws + 4718592);          // 16*4096*32*2   = 4,194,304 B
    bf16* Kb    = (bf16*)(ws + 8912896);
    bf16* Vb    = (bf16*)(ws + 13107200);
    bf16* VTb   = (bf16*)(ws + 17301504);
    bf16* attT  = (bf16*)(ws + 21495808);         // ends at 25,690,112 B

    prep_w_kernel<<<1024, 256, 0, stream>>>(qkv_w, proj_w, wqkv, wproj);
    transpose_x_kernel<<<dim3(128, 8, 2), 256, 0, stream>>>(x, xT);
    qkv_gemm_kernel<<<dim3(32, 6, 2), 256, 0, stream>>>(xT, wqkv, Qb, Kb, Vb);
    transpose_v_kernel<<<dim3(64, 16), 256, 0, stream>>>(Vb, VTb);
    attn_kernel<<<dim3(32, 16), 256, 0, stream>>>(Qb, Kb, VTb, attT);
    proj_gemm_kernel<<<dim3(32, 4, 2), 256, 0, stream>>>(attT, wproj, proj_b, out);
}

// Round 2
// 131.842 us; speedup vs baseline: 1.4364x; 1.4364x over previous
//
#include <hip/hip_runtime.h>
#include <hip/hip_bf16.h>

typedef __bf16 bf16;
typedef __bf16 bf16x8 __attribute__((ext_vector_type(8)));
typedef float f32x4 __attribute__((ext_vector_type(4)));
typedef float f32x16 __attribute__((ext_vector_type(16)));
typedef unsigned int u32x4 __attribute__((ext_vector_type(4)));
typedef unsigned short u16x8 __attribute__((ext_vector_type(8)));

#define EXP2(x) __builtin_amdgcn_exp2f(x)

static __device__ __forceinline__ f32x4 mfma16(bf16x8 a, bf16x8 b, f32x4 c) {
    return __builtin_amdgcn_mfma_f32_16x16x32_bf16(a, b, c, 0, 0, 0);
}
static __device__ __forceinline__ f32x16 mfma32(bf16x8 a, bf16x8 b, f32x16 c) {
    return __builtin_amdgcn_mfma_f32_32x32x16_bf16(a, b, c, 0, 0, 0);
}
static __device__ __forceinline__ unsigned cvt_pk(float lo, float hi) {
    unsigned r;
    asm("v_cvt_pk_bf16_f32 %0, %1, %2" : "=v"(r) : "v"(lo), "v"(hi));
    return r;
}
static __device__ __forceinline__ void perm32swap(unsigned &a, unsigned &b) {
    asm("v_permlane32_swap_b32 %0, %1" : "+v"(a), "+v"(b));
}

// ---------------- Kernel 1: weight convert (+ fold softmax scale*log2e into Q rows) ----
__global__ __launch_bounds__(256) void prep_w_kernel(const float* __restrict__ qkv_w,
                                                     const float* __restrict__ proj_w,
                                                     bf16* __restrict__ wqkv,
                                                     bf16* __restrict__ wproj) {
    int idx = blockIdx.x * 256 + threadIdx.x;
    const float QSCALE = 0.17677669529663689f * 1.4426950408889634f; // hd^-0.5 * log2(e)
    if (idx < 768 * 256) {
        float v = qkv_w[idx];
        if (idx < 256 * 256) v *= QSCALE;   // rows o<256 are the Q projection
        wqkv[idx] = (bf16)v;
    } else {
        int j = idx - 768 * 256;
        wproj[j] = (bf16)proj_w[j];
    }
}

// ---------------- Kernel 2: x [2][256][4096] f32 -> xT [2][4096][256] bf16 ------------
__global__ __launch_bounds__(256) void transpose_x_kernel(const float* __restrict__ x,
                                                          bf16* __restrict__ xT) {
    __shared__ float tile[32][33];
    int b = blockIdx.z, cb = blockIdx.y * 32, nb = blockIdx.x * 32;
    int t = threadIdx.x;
    int tn = t & 31, tc = t >> 5;   // tc in [0,8)
    const float* src = x + ((size_t)b * 256 + cb) * 4096 + nb;
#pragma unroll
    for (int i = 0; i < 4; i++)
        tile[tc + i * 8][tn] = src[(size_t)(tc + i * 8) * 4096 + tn];
    __syncthreads();
    bf16* dst = xT + ((size_t)b * 4096 + nb) * 256 + cb;
#pragma unroll
    for (int i = 0; i < 4; i++)
        dst[(size_t)(tc + i * 8) * 256 + tn] = (bf16)tile[tn][tc + i * 8];
}

// ---------------- Kernel 3: QKV GEMM.  D[n][o] = xT[n][c] * wqkv[o][c]^T --------------
__global__ __launch_bounds__(256) void qkv_gemm_kernel(const bf16* __restrict__ xT,
                                                       const bf16* __restrict__ w,
                                                       bf16* __restrict__ Q,
                                                       bf16* __restrict__ K,
                                                       bf16* __restrict__ V) {
    int b = blockIdx.z;
    int nb = blockIdx.x * 128, ob = blockIdx.y * 128;
    int t = threadIdx.x, wid = t >> 6, lane = t & 63;
    int l15 = lane & 15, g = lane >> 4;
    int wr = wid >> 1, wc = wid & 1;
    const bf16* xrow = xT + ((size_t)b * 4096 + nb + wr * 64 + l15) * 256 + g * 8;
    const bf16* wrow = w + (size_t)(ob + wc * 64 + l15) * 256 + g * 8;
    f32x4 acc[4][4] = {};
    for (int k0 = 0; k0 < 256; k0 += 32) {
        bf16x8 a[4], bb[4];
#pragma unroll
        for (int rt = 0; rt < 4; rt++) a[rt] = *(const bf16x8*)(xrow + rt * 16 * 256 + k0);
#pragma unroll
        for (int cg = 0; cg < 4; cg++) bb[cg] = *(const bf16x8*)(wrow + cg * 16 * 256 + k0);
#pragma unroll
        for (int rt = 0; rt < 4; rt++)
#pragma unroll
            for (int cg = 0; cg < 4; cg++)
                acc[rt][cg] = mfma16(a[rt], bb[cg], acc[rt][cg]);
    }
#pragma unroll
    for (int rt = 0; rt < 4; rt++) {
#pragma unroll
        for (int cg = 0; cg < 4; cg++) {
            int o = ob + wc * 64 + cg * 16 + l15;
            int tsel = o >> 8;           // 0=Q 1=K 2=V
            int h = (o >> 5) & 7;
            int d = o & 31;
            bf16* dst = (tsel == 0 ? Q : (tsel == 1 ? K : V));
#pragma unroll
            for (int i = 0; i < 4; i++) {
                int n = nb + wr * 64 + rt * 16 + g * 4 + i;
                dst[(((size_t)b * 8 + h) * 4096 + n) * 32 + d] = (bf16)acc[rt][cg][i];
            }
        }
    }
}

// ---------------- Kernel 4: V [bh][4096][32] -> VT [bh][32][4096] ---------------------
__global__ __launch_bounds__(256) void transpose_v_kernel(const bf16* __restrict__ V,
                                                          bf16* __restrict__ VT) {
    __shared__ unsigned short tile[64][40];
    int bh = blockIdx.y, nb = blockIdx.x * 64;
    int t = threadIdx.x;
    int rn = t >> 2, d0 = (t & 3) * 8;
    u16x8 vv = *(const u16x8*)((const unsigned short*)V + ((size_t)bh * 4096 + nb + rn) * 32 + d0);
#pragma unroll
    for (int j = 0; j < 8; j++) tile[rn][d0 + j] = vv[j];
    __syncthreads();
    int d = t >> 3, n0 = (t & 7) * 8;
    u16x8 o;
#pragma unroll
    for (int j = 0; j < 8; j++) o[j] = tile[n0 + j][d];
    *(u16x8*)((unsigned short*)VT + ((size_t)bh * 32 + d) * 4096 + nb + n0) = o;
}

// ---------------- Kernel 5: flash attention, swapped-operand 32x32 structure ----------
// grid (32 qblocks of 128, 16 bh), 256 thr = 4 waves, 32 q-rows/wave, KVBLK=64.
// No LDS, no barriers. S^T = mfma32(Kfrag, Qfrag): lane owns q = lane&31;
// its 32 of 64 k-values are in-register (partner lane^32 holds the rest).
// P -> bf16 B-frags via v_cvt_pk_bf16_f32 + v_permlane32_swap_b32.
// O^T = mfma32(VTfrag, Pfrag): lane col = own q -> scalar rescale.
#define PACK(stv, B, OUT) {                                  \
    unsigned _x01 = cvt_pk(stv[B + 0], stv[B + 1]);          \
    unsigned _x23 = cvt_pk(stv[B + 2], stv[B + 3]);          \
    unsigned _y01 = cvt_pk(stv[B + 4], stv[B + 5]);          \
    unsigned _y23 = cvt_pk(stv[B + 6], stv[B + 7]);          \
    perm32swap(_x01, _y01);                                  \
    perm32swap(_x23, _y23);                                  \
    u32x4 _w = {_x01, _x23, _y01, _y23};                     \
    OUT = __builtin_bit_cast(bf16x8, _w); }

__global__ __launch_bounds__(256, 2) void attn_kernel(const bf16* __restrict__ Q,
                                                      const bf16* __restrict__ K,
                                                      const bf16* __restrict__ VT,
                                                      bf16* __restrict__ attT) {
    const int bh = blockIdx.y;
    const int t = threadIdx.x;
    const int wid = t >> 6, lane = t & 63;
    const int l31 = lane & 31, hi = lane >> 5;
    const int q0 = blockIdx.x * 128 + wid * 32;

    const bf16* __restrict__ Qb = Q + (size_t)bh * 4096 * 32;
    const bf16* __restrict__ Kb = K + (size_t)bh * 4096 * 32;
    const bf16* __restrict__ Vb = VT + (size_t)bh * 4096 * 32;   // [32][4096]

    // Q B-frags (col = q = l31), elements d = ks*16 + hi*8 + j
    bf16x8 qf0 = *(const bf16x8*)(Qb + (size_t)(q0 + l31) * 32 + hi * 8);
    bf16x8 qf1 = *(const bf16x8*)(Qb + (size_t)(q0 + l31) * 32 + 16 + hi * 8);

    const bf16* kbase = Kb + (size_t)l31 * 32 + hi * 8;    // + krow*32
    const bf16* vbase = Vb + (size_t)l31 * 4096 + hi * 8;  // + k

    f32x16 o_acc = {};
    float m_run = -INFINITY, l_run = 0.f;

    // prefetch first K tile: A-frag rows k = l31 (+kt*32), elements d = ks*16+hi*8+j
    bf16x8 kf00 = *(const bf16x8*)(kbase);
    bf16x8 kf01 = *(const bf16x8*)(kbase + 16);
    bf16x8 kf10 = *(const bf16x8*)(kbase + 32 * 32);
    bf16x8 kf11 = *(const bf16x8*)(kbase + 32 * 32 + 16);

    for (int kb = 0; kb < 4096; kb += 64) {
        // V frags for this iter (A rows d = l31, elements k)
        bf16x8 vf0 = *(const bf16x8*)(vbase + kb);
        bf16x8 vf1 = *(const bf16x8*)(vbase + kb + 16);
        bf16x8 vf2 = *(const bf16x8*)(vbase + kb + 32);
        bf16x8 vf3 = *(const bf16x8*)(vbase + kb + 48);

        f32x16 z = {};
        f32x16 st0 = mfma32(kf00, qf0, z);
        st0 = mfma32(kf01, qf1, st0);
        f32x16 st1 = mfma32(kf10, qf0, z);
        st1 = mfma32(kf11, qf1, st1);

        // prefetch next K tile (last iter reads into adjacent ws buffer: harmless)
        {
            const bf16* knext = kbase + (size_t)(kb + 64) * 32;
            kf00 = *(const bf16x8*)(knext);
            kf01 = *(const bf16x8*)(knext + 16);
            kf10 = *(const bf16x8*)(knext + 32 * 32);
            kf11 = *(const bf16x8*)(knext + 32 * 32 + 16);
        }

        // ---- in-register softmax (lane owns one q-row; 32 of 64 k local) ----
        float tm[8];
#pragma unroll
        for (int r = 0; r < 8; r++)
            tm[r] = fmaxf(fmaxf(st0[r], st0[r + 8]), fmaxf(st1[r], st1[r + 8]));
#pragma unroll
        for (int s = 4; s >= 1; s >>= 1)
#pragma unroll
            for (int r = 0; r < s; r++) tm[r] = fmaxf(tm[r], tm[r + s]);
        float mt = fmaxf(tm[0], __shfl_xor(tm[0], 32));

        if (!__all(mt <= m_run)) {          // defer-rescale: skip when max didn't grow
            float mnew = fmaxf(m_run, mt);
            float corr = EXP2(m_run - mnew);
            m_run = mnew;
            l_run *= corr;
#pragma unroll
            for (int r = 0; r < 16; r++) o_acc[r] *= corr;
        }

        // P = exp2(S - m) in place
#pragma unroll
        for (int r = 0; r < 16; r++) st0[r] = EXP2(st0[r] - m_run);
#pragma unroll
        for (int r = 0; r < 16; r++) st1[r] = EXP2(st1[r] - m_run);

        // l += row-sum (self 32 + partner 32)
        float s0 = 0.f, s1 = 0.f;
#pragma unroll
        for (int r = 0; r < 16; r++) { s0 += st0[r]; s1 += st1[r]; }
        float ssum = s0 + s1;
        ssum += __shfl_xor(ssum, 32);
        l_run += ssum;

        // pack P into 4 bf16x8 B-frags (k-local = ks4*16 + hi*8 + j)
        bf16x8 pb0, pb1, pb2, pb3;
        PACK(st0, 0, pb0);
        PACK(st0, 8, pb1);
        PACK(st1, 0, pb2);
        PACK(st1, 8, pb3);

        // O^T += V^T P  (rows d, cols q)
        o_acc = mfma32(vf0, pb0, o_acc);
        o_acc = mfma32(vf1, pb1, o_acc);
        o_acc = mfma32(vf2, pb2, o_acc);
        o_acc = mfma32(vf3, pb3, o_acc);
    }

    // epilogue: lane owns q = q0+l31; regs hold d = (r&3)+8*(r>>2)+4*hi
    float inv = __builtin_amdgcn_rcpf(l_run);
    const int b = bh >> 3, h = bh & 7;
    bf16* orow = attT + ((size_t)b * 4096 + q0 + l31) * 256 + h * 32 + 4 * hi;
#pragma unroll
    for (int g = 0; g < 4; g++) {
        unsigned w0 = cvt_pk(o_acc[4 * g + 0] * inv, o_acc[4 * g + 1] * inv);
        unsigned w1 = cvt_pk(o_acc[4 * g + 2] * inv, o_acc[4 * g + 3] * inv);
        uint2 w;
        w.x = w0; w.y = w1;
        *(uint2*)(orow + 8 * g) = w;
    }
}

// ---------------- Kernel 6: proj GEMM. out[b][o][n] = wproj[o][c] * att[c][n] + bias --
__global__ __launch_bounds__(256) void proj_gemm_kernel(const bf16* __restrict__ attT,
                                                        const bf16* __restrict__ w,
                                                        const float* __restrict__ bias,
                                                        float* __restrict__ out) {
    int b = blockIdx.z;
    int nb = blockIdx.x * 128, ob = blockIdx.y * 64;
    int t = threadIdx.x, wid = t >> 6, lane = t & 63;
    int l15 = lane & 15, g = lane >> 4;
    int wr = wid >> 1, wc = wid & 1;
    const bf16* arow = w + (size_t)(ob + wr * 32 + l15) * 256 + g * 8;
    const bf16* brow = attT + ((size_t)b * 4096 + nb + wc * 64 + l15) * 256 + g * 8;
    f32x4 acc[2][4] = {};
    for (int k0 = 0; k0 < 256; k0 += 32) {
        bf16x8 a[2], bb[4];
#pragma unroll
        for (int rt = 0; rt < 2; rt++) a[rt] = *(const bf16x8*)(arow + rt * 16 * 256 + k0);
#pragma unroll
        for (int cg = 0; cg < 4; cg++) bb[cg] = *(const bf16x8*)(brow + cg * 16 * 256 + k0);
#pragma unroll
        for (int rt = 0; rt < 2; rt++)
#pragma unroll
            for (int cg = 0; cg < 4; cg++)
                acc[rt][cg] = mfma16(a[rt], bb[cg], acc[rt][cg]);
    }
#pragma unroll
    for (int rt = 0; rt < 2; rt++)
#pragma unroll
        for (int cg = 0; cg < 4; cg++)
#pragma unroll
            for (int i = 0; i < 4; i++) {
                int o = ob + wr * 32 + rt * 16 + g * 4 + i;
                int n = nb + wc * 64 + cg * 16 + l15;
                out[((size_t)b * 256 + o) * 4096 + n] = acc[rt][cg][i] + bias[o];
            }
}

// ---------------- launch --------------------------------------------------------------
extern "C" void kernel_launch(void* const* d_in, const int* in_sizes, int n_in,
                              void* d_out, int out_size, void* d_ws, size_t ws_size,
                              hipStream_t stream) {
    const float* x      = (const float*)d_in[0];
    const float* qkv_w  = (const float*)d_in[1];
    const float* proj_w = (const float*)d_in[2];
    const float* proj_b = (const float*)d_in[3];
    float* out = (float*)d_out;

    char* ws = (char*)d_ws;
    bf16* xT    = (bf16*)(ws);                    // 2*4096*256*2   = 4,194,304 B
    bf16* wqkv  = (bf16*)(ws + 4194304);          // 768*256*2      =   393,216 B
    bf16* wproj = (bf16*)(ws + 4587520);          // 256*256*2      =   131,072 B
    bf16* Qb    = (bf16*)(ws + 4718592);          // 16*4096*32*2   = 4,194,304 B
    bf16* Kb    = (bf16*)(ws + 8912896);
    bf16* Vb    = (bf16*)(ws + 13107200);
    bf16* VTb   = (bf16*)(ws + 17301504);
    bf16* attT  = (bf16*)(ws + 21495808);         // ends at 25,690,112 B

    prep_w_kernel<<<1024, 256, 0, stream>>>(qkv_w, proj_w, wqkv, wproj);
    transpose_x_kernel<<<dim3(128, 8, 2), 256, 0, stream>>>(x, xT);
    qkv_gemm_kernel<<<dim3(32, 6, 2), 256, 0, stream>>>(xT, wqkv, Qb, Kb, Vb);
    transpose_v_kernel<<<dim3(64, 16), 256, 0, stream>>>(Vb, VTb);
    attn_kernel<<<dim3(32, 16), 256, 0, stream>>>(Qb, Kb, VTb, attT);
    proj_gemm_kernel<<<dim3(32, 4, 2), 256, 0, stream>>>(attT, wproj, proj_b, out);
}